// Round 6
// baseline (208.979 us; speedup 1.0000x reference)
//
#include <hip/hip_runtime.h>
#include <stdint.h>

// ---------------- modular arithmetic ----------------
static constexpr uint32_t P = 2013265921u;         // 15*2^27 + 1
static constexpr int      LOGM = 11;               // per-block DFT size 2048
static constexpr int      MSZ  = 1 << LOGM;

__host__ __device__ constexpr uint32_t neg_pinv32() {
    uint32_t x = 1u;
    for (int i = 0; i < 5; ++i) x *= 2u - P * x;
    return 0u - x;
}
static constexpr uint32_t NEG_PINV = neg_pinv32();
static constexpr uint32_t R1 = (uint32_t)(((uint64_t)1 << 32) % P);
static constexpr uint32_t R2 = (uint32_t)(((uint64_t)R1 * R1) % P);

__device__ __forceinline__ uint32_t mont_mul(uint32_t a, uint32_t b) {
    uint32_t tlo = a * b;
    uint32_t thi = __umulhi(a, b);
    uint32_t m   = tlo * NEG_PINV;
    uint32_t r   = thi + __umulhi(m, P) + (tlo != 0u);   // r < 2P
    uint32_t s   = r - P;
    return s < r ? s : r;
}
__device__ __forceinline__ uint32_t to_mont(uint32_t a) { return mont_mul(a, R2); }

__device__ __forceinline__ uint32_t shoup_mul(uint32_t w, uint32_t wp, uint32_t x) {
    uint32_t q = __umulhi(wp, x);
    uint32_t t = w * x - q * P;          // exact, in [0, 2P)
    uint32_t s = t - P;
    return s < t ? s : t;
}
__device__ __forceinline__ uint32_t add_p(uint32_t a, uint32_t b) {
    uint32_t r = a + b, s = r - P; return s < r ? s : r;
}
__device__ __forceinline__ uint32_t sub_p(uint32_t a, uint32_t b) {
    uint32_t r = a - b, s = r + P; return s < r ? s : r;
}
__device__ __forceinline__ uint4 mm4(uint32_t w, uint4 v) {
    return make_uint4(mont_mul(w, v.x), mont_mul(w, v.y),
                      mont_mul(w, v.z), mont_mul(w, v.w));
}
__device__ __forceinline__ void bf4_sh(uint4& L, uint4& H, uint2 w) {
    uint4 t = make_uint4(shoup_mul(w.x, w.y, H.x), shoup_mul(w.x, w.y, H.y),
                         shoup_mul(w.x, w.y, H.z), shoup_mul(w.x, w.y, H.w));
    uint4 l = L;
    L = make_uint4(add_p(l.x, t.x), add_p(l.y, t.y), add_p(l.z, t.z), add_p(l.w, t.w));
    H = make_uint4(sub_p(l.x, t.x), sub_p(l.y, t.y), sub_p(l.z, t.z), sub_p(l.w, t.w));
}
__device__ __forceinline__ void bf4_mont(uint4& L, uint4& H, uint32_t wm) {
    uint4 t = mm4(wm, H);
    uint4 l = L;
    L = make_uint4(add_p(l.x, t.x), add_p(l.y, t.y), add_p(l.z, t.z), add_p(l.w, t.w));
    H = make_uint4(sub_p(l.x, t.x), sub_p(l.y, t.y), sub_p(l.z, t.z), sub_p(l.w, t.w));
}
__device__ __forceinline__ void bf4_triv(uint4& L, uint4& H) {   // w == 1
    uint4 l = L, h = H;
    L = make_uint4(add_p(l.x, h.x), add_p(l.y, h.y), add_p(l.z, h.z), add_p(l.w, h.w));
    H = make_uint4(sub_p(l.x, h.x), sub_p(l.y, h.y), sub_p(l.z, h.z), sub_p(l.w, h.w));
}

// LDS swizzle, bijective on [0,1024), conflict-free for our access strides.
__device__ __forceinline__ int g_sw(int i) {
    return i ^ (((i >> 3) ^ (i >> 6)) & 7);
}

__device__ __forceinline__ void radix8_sh(uint4 x[8],
        uint2 ta, uint2 tb0, uint2 tb1,
        uint2 tc0, uint2 tc1, uint2 tc2, uint2 tc3) {
    bf4_sh(x[0], x[1], ta);  bf4_sh(x[2], x[3], ta);
    bf4_sh(x[4], x[5], ta);  bf4_sh(x[6], x[7], ta);
    bf4_sh(x[0], x[2], tb0); bf4_sh(x[1], x[3], tb1);
    bf4_sh(x[4], x[6], tb0); bf4_sh(x[5], x[7], tb1);
    bf4_sh(x[0], x[4], tc0); bf4_sh(x[1], x[5], tc1);
    bf4_sh(x[2], x[6], tc2); bf4_sh(x[3], x[7], tc3);
}

// One 2048-pt inverse DFT per 256-thread block (uint4 = 4 batch columns ride
// along). 20 KiB LDS -> 8 blocks/CU -> 32 waves/CU. All three inter-phase
// exchanges split by el bit10 == (tid>>7) in every phase's ownership map, so
// a 16 KiB half-buffer is time-shared between wave-pair halves.
template <bool PASS2>
__global__ __launch_bounds__(256, 7) void intt_pass(
        const uint4* __restrict__ src, uint4* __restrict__ dst,
        const uint32_t* __restrict__ tw,
        const uint32_t* __restrict__ ninv_p)
{
    __shared__ uint4 buf[1024];    // 16 KiB: one bit10-half of the 2048 els
    __shared__ uint2 stab[511];    // 4088 B: Shoup stage twiddles, stages 1..9

    const int      t   = threadIdx.x;        // [0,256)
    const int      wp  = t >> 7;             // wave-pair half (el bit10 owner)
    const uint32_t bid = blockIdx.x;
    // XCD swizzle: XCD k gets contiguous cols [256k,256k+256) -> L2 line share
    const uint32_t c   = ((bid & 7u) << 8) | (bid >> 3);   // i1-column [0,2048)

    // stab[2^(s-1)-1+j] = (W^(j*2^(11-s)), shoup), W = w^2048 -> tw[j<<(21-(s-1))]
#pragma unroll
    for (int q = 0; q < 2; ++q) {
        int e = t + (q << 8);
        if (e < 511) {
            uint32_t ep1 = (uint32_t)e + 1u;
            int sm1 = 31 - __clz((int)ep1);
            uint32_t j = ep1 - (1u << sm1);
            uint32_t w = tw[j << (21 - sm1)];
            uint32_t wps = (uint32_t)((((uint64_t)w) << 32) / P);
            stab[e] = make_uint2(w, wps);
        }
    }

    // global gather, bit-reversal folded: el = 8t+m <- row rev11(el)
    const uint32_t r8 = __brev((uint32_t)t) >> 24;
    uint4 x[8];
#pragma unroll
    for (int m = 0; m < 8; ++m) {
        uint32_t r3 = __brev((uint32_t)m) >> 29;
        x[m] = src[((r3 << 8) | r8) * (uint32_t)MSZ + c];
    }

    // uniform Montgomery constants: u1=Mont(W^512), u2=Mont(W^256), u3=Mont(W^768)
    const uint32_t u1 = to_mont(tw[1u << 20]);
    const uint32_t u2 = to_mont(tw[1u << 19]);
    const uint32_t u3 = to_mont(tw[3u << 19]);

    // ---- phase 0: stages 1-3 (j=0 group; 7 of 12 butterflies are w=1) ----
    bf4_triv(x[0], x[1]);  bf4_triv(x[2], x[3]);
    bf4_triv(x[4], x[5]);  bf4_triv(x[6], x[7]);
    bf4_triv(x[0], x[2]);  bf4_mont(x[1], x[3], u1);
    bf4_triv(x[4], x[6]);  bf4_mont(x[5], x[7], u1);
    bf4_triv(x[0], x[4]);  bf4_mont(x[1], x[5], u2);
    bf4_mont(x[2], x[6], u1); bf4_mont(x[3], x[7], u3);

    const int L1 = t & 7;
    const int b1i = (((t >> 3) << 6) | L1) & 1023;     // phase-1 base (masked)
    // ---- X01: els 8t+m  ->  els b1|(m<<3), sliced by wave-pair ----
    if (wp == 0) {
#pragma unroll
        for (int m = 0; m < 8; ++m) buf[g_sw((8 * t + m) & 1023)] = x[m];
    }
    __syncthreads();
    if (wp == 0) {
#pragma unroll
        for (int m = 0; m < 8; ++m) x[m] = buf[g_sw(b1i | (m << 3))];
    }
    __syncthreads();
    if (wp == 1) {
#pragma unroll
        for (int m = 0; m < 8; ++m) buf[g_sw((8 * t + m) & 1023)] = x[m];
    }
    __syncthreads();
    if (wp == 1) {
#pragma unroll
        for (int m = 0; m < 8; ++m) x[m] = buf[g_sw(b1i | (m << 3))];
    }
    __syncthreads();

    // ---- phase 1: stages 4-6 ----
    radix8_sh(x, stab[7 + L1], stab[15 + L1], stab[23 + L1],
                 stab[31 + L1], stab[39 + L1], stab[47 + L1], stab[55 + L1]);

    const int L2 = t & 63;
    const int b2i = ((((t >> 6) & 1) << 9) | L2);       // phase-2 base (masked)
    // ---- X12: els b1|(m<<3) -> els b2|(m<<6) ----
    if (wp == 0) {
#pragma unroll
        for (int m = 0; m < 8; ++m) buf[g_sw(b1i | (m << 3))] = x[m];
    }
    __syncthreads();
    if (wp == 0) {
#pragma unroll
        for (int m = 0; m < 8; ++m) x[m] = buf[g_sw(b2i | (m << 6))];
    }
    __syncthreads();
    if (wp == 1) {
#pragma unroll
        for (int m = 0; m < 8; ++m) buf[g_sw(b1i | (m << 3))] = x[m];
    }
    __syncthreads();
    if (wp == 1) {
#pragma unroll
        for (int m = 0; m < 8; ++m) x[m] = buf[g_sw(b2i | (m << 6))];
    }
    __syncthreads();

    // ---- phase 2: stages 7-9 ----
    radix8_sh(x, stab[63 + L2], stab[127 + L2], stab[191 + L2],
                 stab[255 + L2], stab[319 + L2], stab[383 + L2], stab[447 + L2]);

    // stage-10/11 twiddles from ONE scattered global load + Montgomery chain:
    // b(lo)=Mont(W^lo); t10=b^2; t110=b; t111=b*Mont(W^512); b(lo+256)=b*Mont(W^256)
    const uint32_t b0m = to_mont(tw[(uint32_t)t << 11]);     // Mont(W^t)
    const uint32_t b1m = mont_mul(b0m, u2);                  // Mont(W^(t+256))

    // pass-1 epilogue constants
    uint32_t nm = 0u, s256 = 0u, step512 = 0u, tm0 = 0u;
    if (PASS2) {
        nm = to_mont(*ninv_p);
    } else {
        s256    = to_mont(tw[c << 8]);              // Mont(w^(256c))
        step512 = mont_mul(s256, s256);             // Mont(w^(512c))
        tm0     = to_mont(tw[c * (uint32_t)t]);     // Mont(w^(c*t))
    }

    // ---- X23 + phase 3 (stages 10-11) + epilogue ----
    // window A: wp0 writes (els b10=0), all read m''∈{0,1}, stage-10 bf
    // window B: wp1 writes (els b10=1), all read m''∈{2,3}, finish + store
    __syncthreads();          // phase-2 regs done everywhere before wp0 write
    if (wp == 0) {
#pragma unroll
        for (int m = 0; m < 8; ++m) buf[g_sw(b2i | (m << 6))] = x[m];
    }
    __syncthreads();
    uint4 y0[2], y1[2], y2[2], y3[2];
#pragma unroll
    for (int gg = 0; gg < 2; ++gg) {
        const int lo = (gg << 8) | t;               // [0,512)
        y0[gg] = buf[g_sw(lo)];                     // el = lo        (m''=0)
        y1[gg] = buf[g_sw(512 | lo)];               // el = lo|512    (m''=1)
        const uint32_t bg  = gg ? b1m : b0m;
        const uint32_t t10 = mont_mul(bg, bg);
        bf4_mont(y0[gg], y1[gg], t10);              // stage 10, pair (0,1)
    }
    __syncthreads();
    if (wp == 1) {
#pragma unroll
        for (int m = 0; m < 8; ++m) buf[g_sw(b2i | (m << 6))] = x[m];
    }
    __syncthreads();
#pragma unroll
    for (int gg = 0; gg < 2; ++gg) {
        const int lo = (gg << 8) | t;
        y2[gg] = buf[g_sw(lo)];                     // el = lo|1024   (m''=2)
        y3[gg] = buf[g_sw(512 | lo)];               // el = lo|1536   (m''=3)
        const uint32_t bg   = gg ? b1m : b0m;
        const uint32_t t10  = mont_mul(bg, bg);
        const uint32_t t111 = mont_mul(bg, u1);
        bf4_mont(y2[gg], y3[gg], t10);              // stage 10, pair (2,3)
        bf4_mont(y0[gg], y2[gg], bg);               // stage 11, pair (0,2)
        bf4_mont(y1[gg], y3[gg], t111);             // stage 11, pair (1,3)

        if (!PASS2) {
            uint32_t tm = gg ? mont_mul(tm0, s256) : tm0;   // Mont(w^(c*lo))
            dst[c * (uint32_t)MSZ + (uint32_t)lo]          = mm4(tm, y0[gg]);
            tm = mont_mul(tm, step512);
            dst[c * (uint32_t)MSZ + (uint32_t)(512 | lo)]  = mm4(tm, y1[gg]);
            tm = mont_mul(tm, step512);
            dst[c * (uint32_t)MSZ + (uint32_t)(1024 | lo)] = mm4(tm, y2[gg]);
            tm = mont_mul(tm, step512);
            dst[c * (uint32_t)MSZ + (uint32_t)(1536 | lo)] = mm4(tm, y3[gg]);
        } else {
            dst[(uint32_t)lo * (uint32_t)MSZ + c]          = mm4(nm, y0[gg]);
            dst[(uint32_t)(512 | lo) * (uint32_t)MSZ + c]  = mm4(nm, y1[gg]);
            dst[(uint32_t)(1024 | lo) * (uint32_t)MSZ + c] = mm4(nm, y2[gg]);
            dst[(uint32_t)(1536 | lo) * (uint32_t)MSZ + c] = mm4(nm, y3[gg]);
        }
    }
}

// ------------------------------- launch ------------------------------------
extern "C" void kernel_launch(void* const* d_in, const int* in_sizes, int n_in,
                              void* d_out, int out_size, void* d_ws, size_t ws_size,
                              hipStream_t stream)
{
    const uint4*    x    = (const uint4*)d_in[0];      // (N, 4) int32 rows
    const uint32_t* tw   = (const uint32_t*)d_in[1];   // w^k, k < 2^21
    const uint32_t* ninv = (const uint32_t*)d_in[2];
    uint4*          out  = (uint4*)d_out;

    intt_pass<false><<<dim3(2048), dim3(256), 0, stream>>>(x, out, tw, ninv);
    intt_pass<true ><<<dim3(2048), dim3(256), 0, stream>>>(out, out, tw, ninv);
}